// Round 3
// baseline (7538.175 us; speedup 1.0000x reference)
//
#include <hip/hip_runtime.h>

#define HW_ (512 * 512)
#define B_ 8
#define H_ 512
#define W_ 512
#define K_ 32
#define CH_ 16
#define CHPIX_ (HW_ / CH_)  // 16384 pixels per chunk

typedef float v2 __attribute__((ext_vector_type(2)));

// ---------------- compact phase A: per-chunk valid count ----------------
__global__ void k_count(const float* __restrict__ seg, int* __restrict__ chunkCnt) {
  const int blk = blockIdx.x;  // b*CH_ + c
  const int t = threadIdx.x;
  const float4* __restrict__ s4 = (const float4*)(seg + (size_t)blk * CHPIX_) + (size_t)t * 16;
  int cnt = 0;
#pragma unroll
  for (int j = 0; j < 16; ++j) {
    float4 v = s4[j];
    cnt += (v.x >= 0.9f) + (v.y >= 0.9f) + (v.z >= 0.9f) + (v.w >= 0.9f);
  }
  __shared__ int red[256];
  red[t] = cnt;
  __syncthreads();
  for (int off = 128; off > 0; off >>= 1) {
    if (t < off) red[t] += red[t + off];
    __syncthreads();
  }
  if (t == 0) chunkCnt[blk] = red[0];
}

// ---------------- compact phase B: per-batch chunk base offsets ----------------
__global__ void k_scan(const int* __restrict__ chunkCnt, int* __restrict__ chunkBase,
                       int* __restrict__ nvalid, int cap) {
  const int t = threadIdx.x;  // b*CH_ + c
  if (t < B_ * CH_) {
    const int b = t / CH_, c = t % CH_;
    int base = 0;
    for (int q = 0; q < c; ++q) base += chunkCnt[b * CH_ + q];
    chunkBase[t] = base;
    if (c == CH_ - 1) nvalid[b] = min(base + chunkCnt[t], cap);
  }
}

// ---------------- compact phase C: ordered compaction + gather + lanes memset ----------------
__global__ void k_fill(const float* __restrict__ seg, const float* __restrict__ emb,
                       const int* __restrict__ chunkBase, unsigned char* __restrict__ lanes,
                       int* __restrict__ idxC, float* __restrict__ embC, int cap) {
  const int blk = blockIdx.x;  // b*CH_ + c
  const int b = blk / CH_;
  const int t = threadIdx.x;
  const size_t pixbase = (size_t)blk * CHPIX_ + (size_t)t * 64;
  const float4* __restrict__ s4 = (const float4*)(seg + pixbase);

  int cnt = 0;
#pragma unroll
  for (int j = 0; j < 16; ++j) {
    float4 v = s4[j];
    cnt += (v.x >= 0.9f) + (v.y >= 0.9f) + (v.z >= 0.9f) + (v.w >= 0.9f);
  }
  __shared__ int pre[256];
  pre[t] = cnt;
  __syncthreads();
  for (int off = 1; off < 256; off <<= 1) {
    int mine = pre[t];
    int add = (t >= off) ? pre[t - off] : 0;
    __syncthreads();
    pre[t] = mine + add;
    __syncthreads();
  }
  int w = chunkBase[blk] + pre[t] - cnt;

  uint4 z = {0u, 0u, 0u, 0u};
  uint4* lz = (uint4*)(lanes + pixbase);
  lz[0] = z; lz[1] = z; lz[2] = z; lz[3] = z;

  const float* __restrict__ eb = emb + (size_t)b * 8 * HW_;
  const int pixInB = (int)(pixbase - (size_t)b * HW_);
  for (int j = 0; j < 16; ++j) {
    float4 v = s4[j];
    float sv[4] = {v.x, v.y, v.z, v.w};
#pragma unroll
    for (int q = 0; q < 4; ++q) {
      if (sv[q] >= 0.9f && w < cap) {
        const int p = pixInB + j * 4 + q;
        idxC[(size_t)b * cap + w] = p;
        float* dst = embC + ((size_t)b * cap + w) * 8;
#pragma unroll
        for (int dd = 0; dd < 8; ++dd) dst[dd] = eb[(size_t)dd * HW_ + p];
        ++w;
      }
    }
  }
}

// ---------------- sequential clustering: 2 batches per wave ----------------
// lanes 0-31: batch 2*blk (centers 0-31); lanes 32-63: batch 2*blk+1
#define STEP(AL, AH, BL, BH, J)                                                            \
  do {                                                                                     \
    v2 ea0 = {AL.x, AL.y}, ea1 = {AL.z, AL.w}, ea2 = {AH.x, AH.y}, ea3 = {AH.z, AH.w};     \
    v2 eb0 = {BL.x, BL.y}, eb1 = {BL.z, BL.w}, eb2 = {BH.x, BH.y}, eb3 = {BH.z, BH.w};     \
    v2 e0 = hi ? eb0 : ea0, e1 = hi ? eb1 : ea1;                                           \
    v2 e2 = hi ? eb2 : ea2, e3 = hi ? eb3 : ea3;                                           \
    v2 t0 = C0 - e0, t1 = C1 - e1, t2 = C2 - e2, t3 = C3 - e3;                             \
    v2 acc = t0 * t0;                                                                      \
    acc += t1 * t1; acc += t2 * t2; acc += t3 * t3;                                        \
    float dsq = acc.x + acc.y;                                                             \
    unsigned db = __float_as_uint(dsq);                                                    \
    db = (cnt > 0.0f) ? db : 0x7F800000u; /* empty center -> +inf bits */                  \
    unsigned mn = db, mr;                                                                  \
    mr = (unsigned)__builtin_amdgcn_update_dpp(0, (int)mn, 0xB1, 0xF, 0xF, true);          \
    mn = mn < mr ? mn : mr;                                                                \
    mr = (unsigned)__builtin_amdgcn_update_dpp(0, (int)mn, 0x4E, 0xF, 0xF, true);          \
    mn = mn < mr ? mn : mr;                                                                \
    mr = (unsigned)__builtin_amdgcn_update_dpp(0, (int)mn, 0x141, 0xF, 0xF, true);         \
    mn = mn < mr ? mn : mr;                                                                \
    mr = (unsigned)__builtin_amdgcn_update_dpp(0, (int)mn, 0x140, 0xF, 0xF, true);         \
    mn = mn < mr ? mn : mr;                                                                \
    unsigned q0 = (unsigned)__builtin_amdgcn_readlane((int)mn, 0);                         \
    unsigned q1 = (unsigned)__builtin_amdgcn_readlane((int)mn, 16);                        \
    unsigned q2 = (unsigned)__builtin_amdgcn_readlane((int)mn, 32);                        \
    unsigned q3 = (unsigned)__builtin_amdgcn_readlane((int)mn, 48);                        \
    unsigned mvA = q0 < q1 ? q0 : q1;                                                      \
    unsigned mvB = q2 < q3 ? q2 : q3;                                                      \
    unsigned long long balA = __ballot(db == mvA);                                         \
    unsigned long long balB = __ballot(db == mvB);                                         \
    int cidA = __ffsll(balA & 0xFFFFFFFFull) - 1;                                          \
    int cidB = __ffsll(balB >> 32) - 1;                                                    \
    bool joinA = mvA < 0x41100000u; /* dsq < 9.0f  <=>  sqrt(d) < 3 */                     \
    bool joinB = mvB < 0x41100000u;                                                        \
    cidA = joinA ? cidA : (nactA < 31 ? nactA : 31);                                       \
    cidB = joinB ? cidB : (nactB < 31 ? nactB : 31);                                       \
    nactA = joinA ? nactA : (nactA < 32 ? nactA + 1 : 32);                                 \
    nactB = joinB ? nactB : (nactB < 32 ? nactB + 1 : 32);                                 \
    int cid_my = hi ? cidB : cidA;                                                         \
    bool join_my = hi ? joinB : joinA;                                                     \
    bool own = (cl == cid_my);                                                             \
    float inv = __builtin_amdgcn_rcpf(cnt + 1.0f);                                         \
    float w = own ? (join_my ? inv : 1.0f) : 0.0f;                                         \
    v2 wv = {w, w};                                                                        \
    C0 -= t0 * wv; C1 -= t1 * wv; C2 -= t2 * wv; C3 -= t3 * wv;                            \
    cnt += own ? 1.0f : 0.0f;                                                              \
    packA |= (unsigned long long)(unsigned)(cidA + 1) << (((J) & 7) * 8);                  \
    packB |= (unsigned long long)(unsigned)(cidB + 1) << (((J) & 7) * 8);                  \
    if (((J) & 7) == 7) {                                                                  \
      if (lane == 0) pA_[(J) >> 3] = packA;                                                \
      if (lane == 32) pB_[(J) >> 3] = packB;                                               \
      packA = 0; packB = 0;                                                                \
    }                                                                                      \
  } while (0)

__global__ __launch_bounds__(64, 1) void k_cluster(const float* __restrict__ embC,
                                                   const int* __restrict__ nvalid,
                                                   unsigned long long* __restrict__ cidPk,
                                                   int cap) {
  const int blk = blockIdx.x;  // 0..3
  const int lane = threadIdx.x;
  const bool hi = lane >= 32;
  const int cl = lane & 31;
  const int bA = blk * 2, bB = blk * 2 + 1;
  const int nA = nvalid[bA], nB = nvalid[bB];
  const int nMax = nA > nB ? nA : nB;
  if (nMax <= 0) return;
  const float4* __restrict__ eA = (const float4*)(embC + (size_t)bA * cap * 8);
  const float4* __restrict__ eB = (const float4*)(embC + (size_t)bB * cap * 8);
  unsigned long long* __restrict__ pA_ = cidPk + (size_t)bA * (HW_ / 8);
  unsigned long long* __restrict__ pB_ = cidPk + (size_t)bB * (HW_ / 8);

  v2 C0 = {0.f, 0.f}, C1 = C0, C2 = C0, C3 = C0;  // 0-init: new-cluster c-t*1 == e exactly
  float cnt = 0.0f;
  int nactA = 0, nactB = 0;
  unsigned long long packA = 0ULL, packB = 0ULL;

  // 2-deep entry slots, consumed every iteration of a ROLLED loop so the
  // compiler must keep them resident (prefetch distance = 2 steps > L2 latency)
  const int i1 = nMax > 1 ? 1 : 0;
  float4 aL0 = eA[0], aH0 = eA[1], bL0 = eB[0], bH0 = eB[1];
  float4 aL1 = eA[2 * i1], aH1 = eA[2 * i1 + 1], bL1 = eB[2 * i1], bH1 = eB[2 * i1 + 1];

  int j = 0;
  for (; j + 2 <= nMax; j += 2) {
    const int p0 = (j + 2) < nMax ? (j + 2) : nMax - 1;
    const int p1 = (j + 3) < nMax ? (j + 3) : nMax - 1;
    STEP(aL0, aH0, bL0, bH0, j);
    aL0 = eA[2 * p0]; aH0 = eA[2 * p0 + 1]; bL0 = eB[2 * p0]; bH0 = eB[2 * p0 + 1];
    STEP(aL1, aH1, bL1, bH1, j + 1);
    aL1 = eA[2 * p1]; aH1 = eA[2 * p1 + 1]; bL1 = eB[2 * p1]; bH1 = eB[2 * p1 + 1];
  }
  if (j < nMax) STEP(aL0, aH0, bL0, bH0, j);
  if (nMax & 7) {  // flush partial packs
    if (lane == 0) pA_[(nMax - 1) >> 3] = packA;
    if (lane == 32) pB_[(nMax - 1) >> 3] = packB;
  }
}

// ---------------- scatter packed cids to the per-pixel lane map ----------------
__global__ void k_scatter(const unsigned long long* __restrict__ cidPk,
                          const int* __restrict__ idxC, const int* __restrict__ nvalid,
                          unsigned char* __restrict__ lanes, int cap) {
  const int b = blockIdx.y;
  const int n = nvalid[b];
  for (int j = blockIdx.x * blockDim.x + threadIdx.x; j < n; j += gridDim.x * blockDim.x) {
    unsigned long long pk = cidPk[(size_t)b * (HW_ / 8) + (j >> 3)];
    unsigned char v = (unsigned char)((pk >> ((j & 7) * 8)) & 0xff);
    lanes[(size_t)b * HW_ + idxC[(size_t)b * cap + j]] = v;
  }
}

// ---------------- per-(b,h) segment sums over 33 lane bins ----------------
__global__ void k_rowsum(const unsigned char* __restrict__ lanes,
                         const float* __restrict__ offp, const float* __restrict__ zp,
                         float* __restrict__ cnt, float* __restrict__ sx,
                         float* __restrict__ sz) {
  const int bh = blockIdx.x;
  const int b = bh >> 9, h = bh & 511;
  __shared__ float sc[33], sxx[33], szz[33];
  const int t = threadIdx.x;
  if (t < 33) { sc[t] = 0.f; sxx[t] = 0.f; szz[t] = 0.f; }
  __syncthreads();
  const size_t base = (size_t)bh * W_;
  for (int x = t; x < W_; x += 256) {
    int ln = lanes[base + x];
    float o = offp[base + x];
    float sig = 1.0f / (1.0f + expf(-o));
    float xa = (float)x + sig;
    float zv = zp[base + x];
    atomicAdd(&sc[ln], 1.0f);
    atomicAdd(&sxx[ln], xa);
    atomicAdd(&szz[ln], zv);
  }
  __syncthreads();
  if (t >= 1 && t < 33) {
    size_t o = ((size_t)b * K_ + (t - 1)) * H_ + h;
    cnt[o] = sc[t]; sx[o] = sxx[t]; sz[o] = szz[t];
  }
}

// ---------------- validity + point assembly ----------------
__global__ void k_final(const float* __restrict__ cnt, const float* __restrict__ sx,
                        const float* __restrict__ sz, float* __restrict__ out) {
  const int bk = blockIdx.x;
  const int b = bk >> 5, k = bk & 31;
  const int h = threadIdx.x;
  const size_t o = (size_t)bk * H_ + h;
  float c = cnt[o];
  float sc_ = c, sn = (c > 0.f) ? 1.f : 0.f;
#pragma unroll
  for (int off = 32; off >= 1; off >>= 1) {
    sc_ += __shfl_down(sc_, off);
    sn += __shfl_down(sn, off);
  }
  __shared__ float rs[8], rn[8], tot[2];
  const int wid = h >> 6, lid = h & 63;
  if (lid == 0) { rs[wid] = sc_; rn[wid] = sn; }
  __syncthreads();
  if (h == 0) {
    float a = 0, bb = 0;
#pragma unroll
    for (int q = 0; q < 8; ++q) { a += rs[q]; bb += rn[q]; }
    tot[0] = a; tot[1] = bb;
  }
  __syncthreads();
  float size = tot[0], nrows = tot[1];
  bool valid = (c > 0.f) && (size >= 50.f) && (nrows >= 2.f);
  float mx = sx[o] / fmaxf(c, 1.f);
  float mz = sz[o] / fmaxf(c, 1.f);
  float xw = (512.0f - ((float)h + 0.5f)) * 0.2f;
  float yw = -(mx - 256.0f) * 0.2f;
  out[((size_t)(b * 3 + 0) * K_ + k) * H_ + h] = valid ? xw : 0.f;
  out[((size_t)(b * 3 + 1) * K_ + k) * H_ + h] = valid ? yw : 0.f;
  out[((size_t)(b * 3 + 2) * K_ + k) * H_ + h] = valid ? mz : 0.f;
  out[(size_t)B_ * 3 * K_ * H_ + (size_t)bk * H_ + h] = valid ? 1.f : 0.f;
}

extern "C" void kernel_launch(void* const* d_in, const int* in_sizes, int n_in,
                              void* d_out, int out_size, void* d_ws, size_t ws_size,
                              hipStream_t stream) {
  const float* seg  = (const float*)d_in[0];
  const float* emb  = (const float*)d_in[1];
  const float* offp = (const float*)d_in[2];
  const float* zp   = (const float*)d_in[3];
  float* out = (float*)d_out;
  char* ws = (char*)d_ws;

  const size_t lanesOff = 0;
  const size_t cntOff   = (size_t)B_ * HW_;
  const size_t sxOff    = cntOff + (size_t)B_ * K_ * H_ * 4;
  const size_t szOff    = sxOff  + (size_t)B_ * K_ * H_ * 4;
  const size_t nvOff    = szOff  + (size_t)B_ * K_ * H_ * 4;
  const size_t ccOff    = nvOff + 256;
  const size_t cbOff    = ccOff + 1024;
  const size_t pkOff    = cbOff + 1024;
  const size_t idxOff   = pkOff + (size_t)B_ * (HW_ / 8) * 8;
  size_t avail = (ws_size > idxOff) ? (ws_size - idxOff) : 0;
  long long capLL = (long long)(avail / ((size_t)B_ * 36));
  if (capLL > (long long)HW_) capLL = HW_;
  if (capLL < 1) capLL = 1;
  const int cap = (int)capLL;
  const size_t embOff = idxOff + (size_t)B_ * cap * 4;

  unsigned char* lanes = (unsigned char*)(ws + lanesOff);
  float* cnt = (float*)(ws + cntOff);
  float* sx  = (float*)(ws + sxOff);
  float* sz  = (float*)(ws + szOff);
  int* nvalid = (int*)(ws + nvOff);
  int* chunkCnt  = (int*)(ws + ccOff);
  int* chunkBase = (int*)(ws + cbOff);
  unsigned long long* cidPk = (unsigned long long*)(ws + pkOff);
  int* idxC   = (int*)(ws + idxOff);
  float* embC = (float*)(ws + embOff);

  k_count<<<B_ * CH_, 256, 0, stream>>>(seg, chunkCnt);
  k_scan<<<1, 128, 0, stream>>>(chunkCnt, chunkBase, nvalid, cap);
  k_fill<<<B_ * CH_, 256, 0, stream>>>(seg, emb, chunkBase, lanes, idxC, embC, cap);
  k_cluster<<<B_ / 2, 64, 0, stream>>>(embC, nvalid, cidPk, cap);
  k_scatter<<<dim3(64, B_), 256, 0, stream>>>(cidPk, idxC, nvalid, lanes, cap);
  k_rowsum<<<B_ * H_, 256, 0, stream>>>(lanes, offp, zp, cnt, sx, sz);
  k_final<<<B_ * K_, H_, 0, stream>>>(cnt, sx, sz, out);
}

// Round 4
// 6242.201 us; speedup vs baseline: 1.2076x; 1.2076x over previous
//
#include <hip/hip_runtime.h>

#define HW_ (512 * 512)
#define B_ 8
#define H_ 512
#define W_ 512
#define K_ 32
#define CH_ 16
#define CHPIX_ (HW_ / CH_)  // 16384 pixels per chunk

typedef float v2 __attribute__((ext_vector_type(2)));

// ---------------- compact phase A: per-chunk valid count ----------------
__global__ void k_count(const float* __restrict__ seg, int* __restrict__ chunkCnt) {
  const int blk = blockIdx.x;  // b*CH_ + c
  const int t = threadIdx.x;
  const float4* __restrict__ s4 = (const float4*)(seg + (size_t)blk * CHPIX_) + (size_t)t * 16;
  int cnt = 0;
#pragma unroll
  for (int j = 0; j < 16; ++j) {
    float4 v = s4[j];
    cnt += (v.x >= 0.9f) + (v.y >= 0.9f) + (v.z >= 0.9f) + (v.w >= 0.9f);
  }
  __shared__ int red[256];
  red[t] = cnt;
  __syncthreads();
  for (int off = 128; off > 0; off >>= 1) {
    if (t < off) red[t] += red[t + off];
    __syncthreads();
  }
  if (t == 0) chunkCnt[blk] = red[0];
}

// ---------------- compact phase B: per-batch chunk base offsets ----------------
__global__ void k_scan(const int* __restrict__ chunkCnt, int* __restrict__ chunkBase,
                       int* __restrict__ nvalid, int cap) {
  const int t = threadIdx.x;  // b*CH_ + c
  if (t < B_ * CH_) {
    const int b = t / CH_, c = t % CH_;
    int base = 0;
    for (int q = 0; q < c; ++q) base += chunkCnt[b * CH_ + q];
    chunkBase[t] = base;
    if (c == CH_ - 1) nvalid[b] = min(base + chunkCnt[t], cap);
  }
}

// ---------------- compact phase C: ordered compaction + gather + lanes memset ----------------
__global__ void k_fill(const float* __restrict__ seg, const float* __restrict__ emb,
                       const int* __restrict__ chunkBase, unsigned char* __restrict__ lanes,
                       int* __restrict__ idxC, float* __restrict__ embC, int cap) {
  const int blk = blockIdx.x;  // b*CH_ + c
  const int b = blk / CH_;
  const int t = threadIdx.x;
  const size_t pixbase = (size_t)blk * CHPIX_ + (size_t)t * 64;
  const float4* __restrict__ s4 = (const float4*)(seg + pixbase);

  int cnt = 0;
#pragma unroll
  for (int j = 0; j < 16; ++j) {
    float4 v = s4[j];
    cnt += (v.x >= 0.9f) + (v.y >= 0.9f) + (v.z >= 0.9f) + (v.w >= 0.9f);
  }
  __shared__ int pre[256];
  pre[t] = cnt;
  __syncthreads();
  for (int off = 1; off < 256; off <<= 1) {
    int mine = pre[t];
    int add = (t >= off) ? pre[t - off] : 0;
    __syncthreads();
    pre[t] = mine + add;
    __syncthreads();
  }
  int w = chunkBase[blk] + pre[t] - cnt;

  uint4 z = {0u, 0u, 0u, 0u};
  uint4* lz = (uint4*)(lanes + pixbase);
  lz[0] = z; lz[1] = z; lz[2] = z; lz[3] = z;

  const float* __restrict__ eb = emb + (size_t)b * 8 * HW_;
  const int pixInB = (int)(pixbase - (size_t)b * HW_);
  for (int j = 0; j < 16; ++j) {
    float4 v = s4[j];
    float sv[4] = {v.x, v.y, v.z, v.w};
#pragma unroll
    for (int q = 0; q < 4; ++q) {
      if (sv[q] >= 0.9f && w < cap) {
        const int p = pixInB + j * 4 + q;
        idxC[(size_t)b * cap + w] = p;
        float* dst = embC + ((size_t)b * cap + w) * 8;
#pragma unroll
        for (int dd = 0; dd < 8; ++dd) dst[dd] = eb[(size_t)dd * HW_ + p];
        ++w;
      }
    }
  }
}

// ---------------- sequential clustering: LDS double-buffered tiles ----------------
// 4 blocks x 1 wave. Lanes 0-31: batch 2*blk; lanes 32-63: batch 2*blk+1.
// LDS: [batch(2)][ring of 64 pixels][8 floats] = 1024 floats (4 KB).
// Tile = 32 pixels; one global_load_lds dwordx4 per batch per tile (64 lanes x 16B = 1KB).

#define TILE_ 32

__device__ __forceinline__ void stage16(const float* g, float* l) {
  __builtin_amdgcn_global_load_lds(
      (const __attribute__((address_space(1))) void*)g,
      (__attribute__((address_space(3))) void*)l, 16, 0, 0);
}

#define CSTEP(JJ)                                                                        \
  do {                                                                                   \
    float4 eL = *(const float4*)(eBase + (JJ) * 8);                                      \
    float4 eH = *(const float4*)(eBase + (JJ) * 8 + 4);                                  \
    v2 e0 = {eL.x, eL.y}, e1 = {eL.z, eL.w};                                             \
    v2 e2 = {eH.x, eH.y}, e3 = {eH.z, eH.w};                                             \
    v2 t0 = C0 - e0, t1 = C1 - e1, t2 = C2 - e2, t3 = C3 - e3;                           \
    v2 a0 = t0 * t0;                                                                     \
    v2 a1 = t2 * t2;                                                                     \
    a0 += t1 * t1;                                                                       \
    a1 += t3 * t3;                                                                       \
    a0 += a1;                                                                            \
    float dsq = a0.x + a0.y;                                                             \
    unsigned db = __float_as_uint(dsq);                                                  \
    db = db > emptyBits ? db : emptyBits; /* empty center -> +inf bits */                \
    unsigned mn = db, mr;                                                                \
    mr = (unsigned)__builtin_amdgcn_update_dpp(0, (int)mn, 0xB1, 0xF, 0xF, true);        \
    mn = mn < mr ? mn : mr;                                                              \
    mr = (unsigned)__builtin_amdgcn_update_dpp(0, (int)mn, 0x4E, 0xF, 0xF, true);        \
    mn = mn < mr ? mn : mr;                                                              \
    mr = (unsigned)__builtin_amdgcn_update_dpp(0, (int)mn, 0x141, 0xF, 0xF, true);       \
    mn = mn < mr ? mn : mr;                                                              \
    mr = (unsigned)__builtin_amdgcn_update_dpp(0, (int)mn, 0x140, 0xF, 0xF, true);       \
    mn = mn < mr ? mn : mr;                                                              \
    unsigned q0 = (unsigned)__builtin_amdgcn_readlane((int)mn, 0);                       \
    unsigned q1 = (unsigned)__builtin_amdgcn_readlane((int)mn, 16);                      \
    unsigned q2 = (unsigned)__builtin_amdgcn_readlane((int)mn, 32);                      \
    unsigned q3 = (unsigned)__builtin_amdgcn_readlane((int)mn, 48);                      \
    unsigned mvA = q0 < q1 ? q0 : q1;                                                    \
    unsigned mvB = q2 < q3 ? q2 : q3;                                                    \
    unsigned long long balA = __ballot(db == mvA);                                       \
    unsigned long long balB = __ballot(db == mvB);                                       \
    int cidA = __ffsll((long long)(balA & 0xFFFFFFFFull)) - 1;                           \
    int cidB = __ffsll((long long)(balB >> 32)) - 1;                                     \
    bool joinA = mvA < 0x41100000u; /* dsq < 9.0f <=> sqrt(dsq) < 3 */                   \
    bool joinB = mvB < 0x41100000u;                                                      \
    cidA = joinA ? cidA : (nactA < 31 ? nactA : 31);                                     \
    cidB = joinB ? cidB : (nactB < 31 ? nactB : 31);                                     \
    nactA += (!joinA && nactA < 32) ? 1 : 0;                                             \
    nactB += (!joinB && nactB < 32) ? 1 : 0;                                             \
    int cid_my = hi ? cidB : cidA;                                                       \
    bool join_my = hi ? joinB : joinA;                                                   \
    bool own = (cl == cid_my);                                                           \
    float w = own ? (join_my ? inv : 1.0f) : 0.0f;                                       \
    v2 wv = {w, w};                                                                      \
    C0 -= t0 * wv;                                                                       \
    C1 -= t1 * wv;                                                                       \
    C2 -= t2 * wv;                                                                       \
    C3 -= t3 * wv;                                                                       \
    cnt += own ? 1.0f : 0.0f;                                                            \
    inv = __builtin_amdgcn_rcpf(cnt + 1.0f);                                             \
    emptyBits = (cnt > 0.f) ? 0u : 0x7F800000u;                                          \
    pk |= (unsigned)(cid_my + 1) << (((JJ) & 3) * 8);                                    \
    if (((JJ) & 3) == 3) {                                                               \
      if ((lane & 31) == 0) *(unsigned*)(cptr + ((JJ) & ~3)) = pk;                       \
      pk = 0u;                                                                           \
    }                                                                                    \
  } while (0)

__global__ __launch_bounds__(64, 1) void k_cluster(const float* __restrict__ embC,
                                                   const int* __restrict__ nvalid,
                                                   unsigned char* __restrict__ cidArr,
                                                   int cap) {
  __shared__ float lds[1024];
  const int blk = blockIdx.x;  // 0..3
  const int lane = threadIdx.x;
  const bool hi = lane >= 32;
  const int cl = lane & 31;
  const int bA = blk * 2, bB = blk * 2 + 1;
  const int nA = nvalid[bA], nB = nvalid[bB];
  const int nMax = nA > nB ? nA : nB;
  if (nMax <= 0) return;
  const int nTiles = (nMax + TILE_ - 1) / TILE_;

  // per-lane staging source: 4 consecutive floats per lane per tile
  const float* srcA = embC + (size_t)bA * cap * 8 + lane * 4;
  const float* srcB = embC + (size_t)bB * cap * 8 + lane * 4;
  unsigned char* cidPtr = cidArr + (size_t)(hi ? bB : bA) * HW_;
  float* ldsMy = lds + (hi ? 512 : 0);

  v2 C0 = {0.f, 0.f}, C1 = C0, C2 = C0, C3 = C0;
  float cnt = 0.f, inv = 1.0f;
  unsigned emptyBits = 0x7F800000u;
  int nactA = 0, nactB = 0;
  unsigned pk = 0u;

  // prologue: stage tile 0 into phase 0
  stage16(srcA, lds + 0);
  stage16(srcB, lds + 512);

  for (int t = 0; t < nTiles; ++t) {
    asm volatile("s_waitcnt vmcnt(0) lgkmcnt(0)" ::: "memory");
    __builtin_amdgcn_sched_barrier(0);
    if (t + 1 < nTiles) {  // stage next tile into the other phase
      const int ph = (t + 1) & 1;
      stage16(srcA + (size_t)(t + 1) * (TILE_ * 8), lds + ph * 256);
      stage16(srcB + (size_t)(t + 1) * (TILE_ * 8), lds + 512 + ph * 256);
    }
    const float* eBase = ldsMy + (t & 1) * 256;
    unsigned char* cptr = cidPtr + t * TILE_;
    CSTEP(0);  CSTEP(1);  CSTEP(2);  CSTEP(3);
    CSTEP(4);  CSTEP(5);  CSTEP(6);  CSTEP(7);
    CSTEP(8);  CSTEP(9);  CSTEP(10); CSTEP(11);
    CSTEP(12); CSTEP(13); CSTEP(14); CSTEP(15);
    CSTEP(16); CSTEP(17); CSTEP(18); CSTEP(19);
    CSTEP(20); CSTEP(21); CSTEP(22); CSTEP(23);
    CSTEP(24); CSTEP(25); CSTEP(26); CSTEP(27);
    CSTEP(28); CSTEP(29); CSTEP(30); CSTEP(31);
  }
}

// ---------------- scatter cid bytes to the per-pixel lane map ----------------
__global__ void k_scatter(const unsigned char* __restrict__ cidArr,
                          const int* __restrict__ idxC, const int* __restrict__ nvalid,
                          unsigned char* __restrict__ lanes, int cap) {
  const int b = blockIdx.y;
  const int n = nvalid[b];
  for (int j = blockIdx.x * blockDim.x + threadIdx.x; j < n; j += gridDim.x * blockDim.x) {
    lanes[(size_t)b * HW_ + idxC[(size_t)b * cap + j]] = cidArr[(size_t)b * HW_ + j];
  }
}

// ---------------- per-(b,h) segment sums over 33 lane bins ----------------
__global__ void k_rowsum(const unsigned char* __restrict__ lanes,
                         const float* __restrict__ offp, const float* __restrict__ zp,
                         float* __restrict__ cnt, float* __restrict__ sx,
                         float* __restrict__ sz) {
  const int bh = blockIdx.x;
  const int b = bh >> 9, h = bh & 511;
  __shared__ float sc[33], sxx[33], szz[33];
  const int t = threadIdx.x;
  if (t < 33) { sc[t] = 0.f; sxx[t] = 0.f; szz[t] = 0.f; }
  __syncthreads();
  const size_t base = (size_t)bh * W_;
  for (int x = t; x < W_; x += 256) {
    int ln = lanes[base + x];
    float o = offp[base + x];
    float sig = 1.0f / (1.0f + expf(-o));
    float xa = (float)x + sig;
    float zv = zp[base + x];
    atomicAdd(&sc[ln], 1.0f);
    atomicAdd(&sxx[ln], xa);
    atomicAdd(&szz[ln], zv);
  }
  __syncthreads();
  if (t >= 1 && t < 33) {
    size_t o = ((size_t)b * K_ + (t - 1)) * H_ + h;
    cnt[o] = sc[t]; sx[o] = sxx[t]; sz[o] = szz[t];
  }
}

// ---------------- validity + point assembly ----------------
__global__ void k_final(const float* __restrict__ cnt, const float* __restrict__ sx,
                        const float* __restrict__ sz, float* __restrict__ out) {
  const int bk = blockIdx.x;
  const int b = bk >> 5, k = bk & 31;
  const int h = threadIdx.x;
  const size_t o = (size_t)bk * H_ + h;
  float c = cnt[o];
  float sc_ = c, sn = (c > 0.f) ? 1.f : 0.f;
#pragma unroll
  for (int off = 32; off >= 1; off >>= 1) {
    sc_ += __shfl_down(sc_, off);
    sn += __shfl_down(sn, off);
  }
  __shared__ float rs[8], rn[8], tot[2];
  const int wid = h >> 6, lid = h & 63;
  if (lid == 0) { rs[wid] = sc_; rn[wid] = sn; }
  __syncthreads();
  if (h == 0) {
    float a = 0, bb = 0;
#pragma unroll
    for (int q = 0; q < 8; ++q) { a += rs[q]; bb += rn[q]; }
    tot[0] = a; tot[1] = bb;
  }
  __syncthreads();
  float size = tot[0], nrows = tot[1];
  bool valid = (c > 0.f) && (size >= 50.f) && (nrows >= 2.f);
  float mx = sx[o] / fmaxf(c, 1.f);
  float mz = sz[o] / fmaxf(c, 1.f);
  float xw = (512.0f - ((float)h + 0.5f)) * 0.2f;
  float yw = -(mx - 256.0f) * 0.2f;
  out[((size_t)(b * 3 + 0) * K_ + k) * H_ + h] = valid ? xw : 0.f;
  out[((size_t)(b * 3 + 1) * K_ + k) * H_ + h] = valid ? yw : 0.f;
  out[((size_t)(b * 3 + 2) * K_ + k) * H_ + h] = valid ? mz : 0.f;
  out[(size_t)B_ * 3 * K_ * H_ + (size_t)bk * H_ + h] = valid ? 1.f : 0.f;
}

extern "C" void kernel_launch(void* const* d_in, const int* in_sizes, int n_in,
                              void* d_out, int out_size, void* d_ws, size_t ws_size,
                              hipStream_t stream) {
  const float* seg  = (const float*)d_in[0];
  const float* emb  = (const float*)d_in[1];
  const float* offp = (const float*)d_in[2];
  const float* zp   = (const float*)d_in[3];
  float* out = (float*)d_out;
  char* ws = (char*)d_ws;

  const size_t lanesOff = 0;
  const size_t cntOff   = (size_t)B_ * HW_;
  const size_t sxOff    = cntOff + (size_t)B_ * K_ * H_ * 4;
  const size_t szOff    = sxOff  + (size_t)B_ * K_ * H_ * 4;
  const size_t nvOff    = szOff  + (size_t)B_ * K_ * H_ * 4;
  const size_t ccOff    = nvOff + 256;
  const size_t cbOff    = ccOff + 1024;
  const size_t cidOff   = cbOff + 1024;                      // u8 [B][HW_] = 2 MiB
  const size_t idxOff   = cidOff + (size_t)B_ * HW_;
  size_t avail = (ws_size > idxOff + 4096) ? (ws_size - idxOff - 4096) : 0;  // 4KB staging slack
  long long capLL = (long long)(avail / ((size_t)B_ * 36));  // 4B idx + 32B emb per entry
  if (capLL > (long long)HW_) capLL = HW_;
  if (capLL < 1) capLL = 1;
  const int cap = (int)capLL;
  const size_t embOff = idxOff + (size_t)B_ * cap * 4;

  unsigned char* lanes = (unsigned char*)(ws + lanesOff);
  float* cnt = (float*)(ws + cntOff);
  float* sx  = (float*)(ws + sxOff);
  float* sz  = (float*)(ws + szOff);
  int* nvalid = (int*)(ws + nvOff);
  int* chunkCnt  = (int*)(ws + ccOff);
  int* chunkBase = (int*)(ws + cbOff);
  unsigned char* cidArr = (unsigned char*)(ws + cidOff);
  int* idxC   = (int*)(ws + idxOff);
  float* embC = (float*)(ws + embOff);

  k_count<<<B_ * CH_, 256, 0, stream>>>(seg, chunkCnt);
  k_scan<<<1, 128, 0, stream>>>(chunkCnt, chunkBase, nvalid, cap);
  k_fill<<<B_ * CH_, 256, 0, stream>>>(seg, emb, chunkBase, lanes, idxC, embC, cap);
  k_cluster<<<B_ / 2, 64, 0, stream>>>(embC, nvalid, cidArr, cap);
  k_scatter<<<dim3(64, B_), 256, 0, stream>>>(cidArr, idxC, nvalid, lanes, cap);
  k_rowsum<<<B_ * H_, 256, 0, stream>>>(lanes, offp, zp, cnt, sx, sz);
  k_final<<<B_ * K_, H_, 0, stream>>>(cnt, sx, sz, out);
}

// Round 5
// 3798.897 us; speedup vs baseline: 1.9843x; 1.6432x over previous
//
#include <hip/hip_runtime.h>

#define HW_ (512 * 512)
#define B_ 8
#define H_ 512
#define W_ 512
#define K_ 32
#define CH_ 16
#define CHPIX_ (HW_ / CH_)  // 16384 pixels per chunk

typedef float v2 __attribute__((ext_vector_type(2)));

// ---------------- compact phase A: per-chunk valid count ----------------
__global__ void k_count(const float* __restrict__ seg, int* __restrict__ chunkCnt) {
  const int blk = blockIdx.x;  // b*CH_ + c
  const int t = threadIdx.x;
  const float4* __restrict__ s4 = (const float4*)(seg + (size_t)blk * CHPIX_) + (size_t)t * 16;
  int cnt = 0;
#pragma unroll
  for (int j = 0; j < 16; ++j) {
    float4 v = s4[j];
    cnt += (v.x >= 0.9f) + (v.y >= 0.9f) + (v.z >= 0.9f) + (v.w >= 0.9f);
  }
  __shared__ int red[256];
  red[t] = cnt;
  __syncthreads();
  for (int off = 128; off > 0; off >>= 1) {
    if (t < off) red[t] += red[t + off];
    __syncthreads();
  }
  if (t == 0) chunkCnt[blk] = red[0];
}

// ---------------- compact phase B: per-batch chunk base offsets ----------------
__global__ void k_scan(const int* __restrict__ chunkCnt, int* __restrict__ chunkBase,
                       int* __restrict__ nvalid, int cap) {
  const int t = threadIdx.x;  // b*CH_ + c
  if (t < B_ * CH_) {
    const int b = t / CH_, c = t % CH_;
    int base = 0;
    for (int q = 0; q < c; ++q) base += chunkCnt[b * CH_ + q];
    chunkBase[t] = base;
    if (c == CH_ - 1) nvalid[b] = min(base + chunkCnt[t], cap);
  }
}

// ---------------- compact phase C: ordered compaction + gather + lanes memset ----------------
__global__ void k_fill(const float* __restrict__ seg, const float* __restrict__ emb,
                       const int* __restrict__ chunkBase, unsigned char* __restrict__ lanes,
                       int* __restrict__ idxC, float* __restrict__ embC, int cap) {
  const int blk = blockIdx.x;  // b*CH_ + c
  const int b = blk / CH_;
  const int t = threadIdx.x;
  const size_t pixbase = (size_t)blk * CHPIX_ + (size_t)t * 64;
  const float4* __restrict__ s4 = (const float4*)(seg + pixbase);

  int cnt = 0;
#pragma unroll
  for (int j = 0; j < 16; ++j) {
    float4 v = s4[j];
    cnt += (v.x >= 0.9f) + (v.y >= 0.9f) + (v.z >= 0.9f) + (v.w >= 0.9f);
  }
  __shared__ int pre[256];
  pre[t] = cnt;
  __syncthreads();
  for (int off = 1; off < 256; off <<= 1) {
    int mine = pre[t];
    int add = (t >= off) ? pre[t - off] : 0;
    __syncthreads();
    pre[t] = mine + add;
    __syncthreads();
  }
  int w = chunkBase[blk] + pre[t] - cnt;

  uint4 z = {0u, 0u, 0u, 0u};
  uint4* lz = (uint4*)(lanes + pixbase);
  lz[0] = z; lz[1] = z; lz[2] = z; lz[3] = z;

  const float* __restrict__ eb = emb + (size_t)b * 8 * HW_;
  const int pixInB = (int)(pixbase - (size_t)b * HW_);
  for (int j = 0; j < 16; ++j) {
    float4 v = s4[j];
    float sv[4] = {v.x, v.y, v.z, v.w};
#pragma unroll
    for (int q = 0; q < 4; ++q) {
      if (sv[q] >= 0.9f && w < cap) {
        const int p = pixInB + j * 4 + q;
        idxC[(size_t)b * cap + w] = p;
        float* dst = embC + ((size_t)b * cap + w) * 8;
#pragma unroll
        for (int dd = 0; dd < 8; ++dd) dst[dd] = eb[(size_t)dd * HW_ + p];
        ++w;
      }
    }
  }
}

// ---------------- sequential clustering: 1 batch/wave, reg-slot pipeline ----------------
// 8 blocks x 1 wave. Centers on lanes 0-31 (mirrored on 32-63).
// LDS: 2 phases x 256 floats (2KB). Tile = 32 pixels; 1 global_load_lds/tile.
// Pixel slots: 4 float4-pairs rotated in registers, reloaded 4 steps ahead.

#define TILE_ 32

__device__ __forceinline__ void stage16(const float* g, float* l) {
  __builtin_amdgcn_global_load_lds(
      (const __attribute__((address_space(1))) void*)g,
      (__attribute__((address_space(3))) void*)l, 16, 0, 0);
}

#define RELOAD(SL, SH, BASE, OFF)                  \
  do {                                             \
    SL = *(const float4*)((BASE) + (OFF) * 8);     \
    SH = *(const float4*)((BASE) + (OFF) * 8 + 4); \
  } while (0)

#define STEPP(J, EL, EH)                                                              \
  do {                                                                                \
    v2 e0 = {EL.x, EL.y}, e1 = {EL.z, EL.w}, e2 = {EH.x, EH.y}, e3 = {EH.z, EH.w};    \
    v2 t0 = C0 - e0, t1 = C1 - e1, t2 = C2 - e2, t3 = C3 - e3;                        \
    v2 aa = t0 * t0;                                                                  \
    v2 bb = t2 * t2;                                                                  \
    aa = t1 * t1 + aa;                                                                \
    bb = t3 * t3 + bb;                                                                \
    aa += bb;                                                                         \
    float dsq = aa.x + aa.y;                                                          \
    unsigned db = __float_as_uint(dsq);                                               \
    unsigned dbm = db > emptyBits ? db : emptyBits; /* empty center -> inf bits */    \
    unsigned mn = dbm, mr;                                                            \
    mr = (unsigned)__builtin_amdgcn_update_dpp(0, (int)mn, 0xB1, 0xF, 0xF, true);     \
    mn = mn < mr ? mn : mr;                                                           \
    mr = (unsigned)__builtin_amdgcn_update_dpp(0, (int)mn, 0x4E, 0xF, 0xF, true);     \
    mn = mn < mr ? mn : mr;                                                           \
    mr = (unsigned)__builtin_amdgcn_update_dpp(0, (int)mn, 0x141, 0xF, 0xF, true);    \
    mn = mn < mr ? mn : mr;                                                           \
    mr = (unsigned)__builtin_amdgcn_update_dpp(0, (int)mn, 0x140, 0xF, 0xF, true);    \
    mn = mn < mr ? mn : mr;                                                           \
    unsigned q0 = (unsigned)__builtin_amdgcn_readlane((int)mn, 0);                    \
    unsigned q1 = (unsigned)__builtin_amdgcn_readlane((int)mn, 16);                   \
    unsigned mv = q0 < q1 ? q0 : q1;                                                  \
    unsigned long long bal = __ballot(dbm == mv);                                     \
    int cidmin = __ffsll((long long)(bal & 0xFFFFFFFFull)) - 1;                       \
    bool join = mv < 0x41100000u; /* dsq < 9.0f <=> sqrt(dsq) < 3 */                  \
    int cid = join ? cidmin : (nact < 31 ? nact : 31);                                \
    nact += (!join && nact < 32) ? 1 : 0;                                             \
    bool own = (cl == cid);                                                           \
    float w = own ? (join ? inv : 1.0f) : 0.0f;                                       \
    v2 wv = {w, w};                                                                   \
    C0 -= t0 * wv;                                                                    \
    C1 -= t1 * wv;                                                                    \
    C2 -= t2 * wv;                                                                    \
    C3 -= t3 * wv;                                                                    \
    cnt += own ? 1.0f : 0.0f;                                                         \
    inv = __builtin_amdgcn_rcpf(cnt + 1.0f);                                          \
    emptyBits = (cnt > 0.f) ? 0u : 0x7F800000u;                                       \
    pk |= (unsigned long long)(unsigned)(cid + 1) << (((J) & 7) * 8);                 \
    if (((J) & 7) == 7) {                                                             \
      if (lane == 0) *(unsigned long long*)(cptr + ((J) & ~7)) = pk;                  \
      pk = 0ULL;                                                                      \
    }                                                                                 \
  } while (0)

__global__ __launch_bounds__(64, 1) void k_cluster(const float* __restrict__ embC,
                                                   const int* __restrict__ nvalid,
                                                   unsigned char* __restrict__ cidArr,
                                                   int cap) {
  __shared__ float lds[512];
  const int b = blockIdx.x;  // one batch per block
  const int lane = threadIdx.x;
  const int cl = lane & 31;  // my center id (upper half mirrors lower)
  const int n = nvalid[b];
  if (n <= 0) return;
  const int nTiles = (n + TILE_ - 1) / TILE_;

  const float* src = embC + (size_t)b * cap * 8 + lane * 4;
  unsigned char* cidB = cidArr + (size_t)b * HW_;

  v2 C0 = {0.f, 0.f}, C1 = C0, C2 = C0, C3 = C0;
  float cnt = 0.f, inv = 1.0f;
  unsigned emptyBits = 0x7F800000u;
  int nact = 0;
  unsigned long long pk = 0ULL;

  // prologue: stage tile 0, wait, load slots 0-3
  stage16(src, lds);
  asm volatile("s_waitcnt vmcnt(0)" ::: "memory");
  __builtin_amdgcn_sched_barrier(0);
  float4 s0L, s0H, s1L, s1H, s2L, s2H, s3L, s3H;
  RELOAD(s0L, s0H, lds, 0);
  RELOAD(s1L, s1H, lds, 1);
  RELOAD(s2L, s2H, lds, 2);
  RELOAD(s3L, s3H, lds, 3);

  for (int ti = 0; ti < nTiles; ++ti) {
    const float* eBase = lds + (ti & 1) * 256;
    unsigned char* cptr = cidB + ti * TILE_;
    if (ti + 1 < nTiles)  // stage next tile into the other phase
      stage16(src + (size_t)(ti + 1) * 256, lds + ((ti + 1) & 1) * 256);

    STEPP(0, s0L, s0H);  RELOAD(s0L, s0H, eBase, 4);
    STEPP(1, s1L, s1H);  RELOAD(s1L, s1H, eBase, 5);
    STEPP(2, s2L, s2H);  RELOAD(s2L, s2H, eBase, 6);
    STEPP(3, s3L, s3H);  RELOAD(s3L, s3H, eBase, 7);
    STEPP(4, s0L, s0H);  RELOAD(s0L, s0H, eBase, 8);
    STEPP(5, s1L, s1H);  RELOAD(s1L, s1H, eBase, 9);
    STEPP(6, s2L, s2H);  RELOAD(s2L, s2H, eBase, 10);
    STEPP(7, s3L, s3H);  RELOAD(s3L, s3H, eBase, 11);
    STEPP(8, s0L, s0H);  RELOAD(s0L, s0H, eBase, 12);
    STEPP(9, s1L, s1H);  RELOAD(s1L, s1H, eBase, 13);
    STEPP(10, s2L, s2H); RELOAD(s2L, s2H, eBase, 14);
    STEPP(11, s3L, s3H); RELOAD(s3L, s3H, eBase, 15);
    STEPP(12, s0L, s0H); RELOAD(s0L, s0H, eBase, 16);
    STEPP(13, s1L, s1H); RELOAD(s1L, s1H, eBase, 17);
    STEPP(14, s2L, s2H); RELOAD(s2L, s2H, eBase, 18);
    STEPP(15, s3L, s3H); RELOAD(s3L, s3H, eBase, 19);
    STEPP(16, s0L, s0H); RELOAD(s0L, s0H, eBase, 20);
    STEPP(17, s1L, s1H); RELOAD(s1L, s1H, eBase, 21);
    STEPP(18, s2L, s2H); RELOAD(s2L, s2H, eBase, 22);
    STEPP(19, s3L, s3H); RELOAD(s3L, s3H, eBase, 23);
    STEPP(20, s0L, s0H); RELOAD(s0L, s0H, eBase, 24);
    STEPP(21, s1L, s1H); RELOAD(s1L, s1H, eBase, 25);
    STEPP(22, s2L, s2H); RELOAD(s2L, s2H, eBase, 26);
    STEPP(23, s3L, s3H); RELOAD(s3L, s3H, eBase, 27);
    STEPP(24, s0L, s0H); RELOAD(s0L, s0H, eBase, 28);
    STEPP(25, s1L, s1H); RELOAD(s1L, s1H, eBase, 29);
    STEPP(26, s2L, s2H); RELOAD(s2L, s2H, eBase, 30);
    STEPP(27, s3L, s3H); RELOAD(s3L, s3H, eBase, 31);
    STEPP(28, s0L, s0H);
    STEPP(29, s1L, s1H);
    STEPP(30, s2L, s2H);
    STEPP(31, s3L, s3H);

    if (ti + 1 < nTiles) {
      // stage(ti+1) is the oldest of <=9 outstanding VMEM ops (1 stage + up to
      // 8 lane-0 stores); in-order retirement => vmcnt(4) <=> stage arrived.
      asm volatile("s_waitcnt vmcnt(4)" ::: "memory");
      __builtin_amdgcn_sched_barrier(0);
      const float* nBase = lds + ((ti + 1) & 1) * 256;
      RELOAD(s0L, s0H, nBase, 0);
      RELOAD(s1L, s1H, nBase, 1);
      RELOAD(s2L, s2H, nBase, 2);
      RELOAD(s3L, s3H, nBase, 3);
    }
  }
}

// ---------------- scatter cid bytes to the per-pixel lane map ----------------
__global__ void k_scatter(const unsigned char* __restrict__ cidArr,
                          const int* __restrict__ idxC, const int* __restrict__ nvalid,
                          unsigned char* __restrict__ lanes, int cap) {
  const int b = blockIdx.y;
  const int n = nvalid[b];
  for (int j = blockIdx.x * blockDim.x + threadIdx.x; j < n; j += gridDim.x * blockDim.x) {
    lanes[(size_t)b * HW_ + idxC[(size_t)b * cap + j]] = cidArr[(size_t)b * HW_ + j];
  }
}

// ---------------- per-(b,h) segment sums over 33 lane bins ----------------
__global__ void k_rowsum(const unsigned char* __restrict__ lanes,
                         const float* __restrict__ offp, const float* __restrict__ zp,
                         float* __restrict__ cnt, float* __restrict__ sx,
                         float* __restrict__ sz) {
  const int bh = blockIdx.x;
  const int b = bh >> 9, h = bh & 511;
  __shared__ float sc[33], sxx[33], szz[33];
  const int t = threadIdx.x;
  if (t < 33) { sc[t] = 0.f; sxx[t] = 0.f; szz[t] = 0.f; }
  __syncthreads();
  const size_t base = (size_t)bh * W_;
  for (int x = t; x < W_; x += 256) {
    int ln = lanes[base + x];
    float o = offp[base + x];
    float sig = 1.0f / (1.0f + expf(-o));
    float xa = (float)x + sig;
    float zv = zp[base + x];
    atomicAdd(&sc[ln], 1.0f);
    atomicAdd(&sxx[ln], xa);
    atomicAdd(&szz[ln], zv);
  }
  __syncthreads();
  if (t >= 1 && t < 33) {
    size_t o = ((size_t)b * K_ + (t - 1)) * H_ + h;
    cnt[o] = sc[t]; sx[o] = sxx[t]; sz[o] = szz[t];
  }
}

// ---------------- validity + point assembly ----------------
__global__ void k_final(const float* __restrict__ cnt, const float* __restrict__ sx,
                        const float* __restrict__ sz, float* __restrict__ out) {
  const int bk = blockIdx.x;
  const int b = bk >> 5, k = bk & 31;
  const int h = threadIdx.x;
  const size_t o = (size_t)bk * H_ + h;
  float c = cnt[o];
  float sc_ = c, sn = (c > 0.f) ? 1.f : 0.f;
#pragma unroll
  for (int off = 32; off >= 1; off >>= 1) {
    sc_ += __shfl_down(sc_, off);
    sn += __shfl_down(sn, off);
  }
  __shared__ float rs[8], rn[8], tot[2];
  const int wid = h >> 6, lid = h & 63;
  if (lid == 0) { rs[wid] = sc_; rn[wid] = sn; }
  __syncthreads();
  if (h == 0) {
    float a = 0, bb = 0;
#pragma unroll
    for (int q = 0; q < 8; ++q) { a += rs[q]; bb += rn[q]; }
    tot[0] = a; tot[1] = bb;
  }
  __syncthreads();
  float size = tot[0], nrows = tot[1];
  bool valid = (c > 0.f) && (size >= 50.f) && (nrows >= 2.f);
  float mx = sx[o] / fmaxf(c, 1.f);
  float mz = sz[o] / fmaxf(c, 1.f);
  float xw = (512.0f - ((float)h + 0.5f)) * 0.2f;
  float yw = -(mx - 256.0f) * 0.2f;
  out[((size_t)(b * 3 + 0) * K_ + k) * H_ + h] = valid ? xw : 0.f;
  out[((size_t)(b * 3 + 1) * K_ + k) * H_ + h] = valid ? yw : 0.f;
  out[((size_t)(b * 3 + 2) * K_ + k) * H_ + h] = valid ? mz : 0.f;
  out[(size_t)B_ * 3 * K_ * H_ + (size_t)bk * H_ + h] = valid ? 1.f : 0.f;
}

extern "C" void kernel_launch(void* const* d_in, const int* in_sizes, int n_in,
                              void* d_out, int out_size, void* d_ws, size_t ws_size,
                              hipStream_t stream) {
  const float* seg  = (const float*)d_in[0];
  const float* emb  = (const float*)d_in[1];
  const float* offp = (const float*)d_in[2];
  const float* zp   = (const float*)d_in[3];
  float* out = (float*)d_out;
  char* ws = (char*)d_ws;

  const size_t lanesOff = 0;
  const size_t cntOff   = (size_t)B_ * HW_;
  const size_t sxOff    = cntOff + (size_t)B_ * K_ * H_ * 4;
  const size_t szOff    = sxOff  + (size_t)B_ * K_ * H_ * 4;
  const size_t nvOff    = szOff  + (size_t)B_ * K_ * H_ * 4;
  const size_t ccOff    = nvOff + 256;
  const size_t cbOff    = ccOff + 1024;
  const size_t cidOff   = cbOff + 1024;                      // u8 [B][HW_] = 2 MiB
  const size_t idxOff   = cidOff + (size_t)B_ * HW_;
  size_t avail = (ws_size > idxOff + 4096) ? (ws_size - idxOff - 4096) : 0;  // staging slack
  long long capLL = (long long)(avail / ((size_t)B_ * 36));  // 4B idx + 32B emb per entry
  if (capLL > (long long)HW_) capLL = HW_;
  if (capLL < 1) capLL = 1;
  const int cap = (int)capLL;
  const size_t embOff = idxOff + (size_t)B_ * cap * 4;

  unsigned char* lanes = (unsigned char*)(ws + lanesOff);
  float* cnt = (float*)(ws + cntOff);
  float* sx  = (float*)(ws + sxOff);
  float* sz  = (float*)(ws + szOff);
  int* nvalid = (int*)(ws + nvOff);
  int* chunkCnt  = (int*)(ws + ccOff);
  int* chunkBase = (int*)(ws + cbOff);
  unsigned char* cidArr = (unsigned char*)(ws + cidOff);
  int* idxC   = (int*)(ws + idxOff);
  float* embC = (float*)(ws + embOff);

  k_count<<<B_ * CH_, 256, 0, stream>>>(seg, chunkCnt);
  k_scan<<<1, 128, 0, stream>>>(chunkCnt, chunkBase, nvalid, cap);
  k_fill<<<B_ * CH_, 256, 0, stream>>>(seg, emb, chunkBase, lanes, idxC, embC, cap);
  k_cluster<<<B_, 64, 0, stream>>>(embC, nvalid, cidArr, cap);
  k_scatter<<<dim3(64, B_), 256, 0, stream>>>(cidArr, idxC, nvalid, lanes, cap);
  k_rowsum<<<B_ * H_, 256, 0, stream>>>(lanes, offp, zp, cnt, sx, sz);
  k_final<<<B_ * K_, H_, 0, stream>>>(cnt, sx, sz, out);
}

// Round 6
// 3118.926 us; speedup vs baseline: 2.4169x; 1.2180x over previous
//
#include <hip/hip_runtime.h>

#define HW_ (512 * 512)
#define B_ 8
#define H_ 512
#define W_ 512
#define K_ 32
#define CH_ 16
#define CHPIX_ (HW_ / CH_)  // 16384 pixels per chunk

// ---------------- compact phase A: per-chunk valid count ----------------
__global__ void k_count(const float* __restrict__ seg, int* __restrict__ chunkCnt) {
  const int blk = blockIdx.x;  // b*CH_ + c
  const int t = threadIdx.x;
  const float4* __restrict__ s4 = (const float4*)(seg + (size_t)blk * CHPIX_) + (size_t)t * 16;
  int cnt = 0;
#pragma unroll
  for (int j = 0; j < 16; ++j) {
    float4 v = s4[j];
    cnt += (v.x >= 0.9f) + (v.y >= 0.9f) + (v.z >= 0.9f) + (v.w >= 0.9f);
  }
  __shared__ int red[256];
  red[t] = cnt;
  __syncthreads();
  for (int off = 128; off > 0; off >>= 1) {
    if (t < off) red[t] += red[t + off];
    __syncthreads();
  }
  if (t == 0) chunkCnt[blk] = red[0];
}

// ---------------- compact phase B: per-batch chunk base offsets ----------------
__global__ void k_scan(const int* __restrict__ chunkCnt, int* __restrict__ chunkBase,
                       int* __restrict__ nvalid, int cap) {
  const int t = threadIdx.x;  // b*CH_ + c
  if (t < B_ * CH_) {
    const int b = t / CH_, c = t % CH_;
    int base = 0;
    for (int q = 0; q < c; ++q) base += chunkCnt[b * CH_ + q];
    chunkBase[t] = base;
    if (c == CH_ - 1) nvalid[b] = min(base + chunkCnt[t], cap);
  }
}

// ---------------- compact phase C: ordered compaction + gather + lanes memset ----------------
__global__ void k_fill(const float* __restrict__ seg, const float* __restrict__ emb,
                       const int* __restrict__ chunkBase, unsigned char* __restrict__ lanes,
                       int* __restrict__ idxC, float* __restrict__ embC, int cap) {
  const int blk = blockIdx.x;  // b*CH_ + c
  const int b = blk / CH_;
  const int t = threadIdx.x;
  const size_t pixbase = (size_t)blk * CHPIX_ + (size_t)t * 64;
  const float4* __restrict__ s4 = (const float4*)(seg + pixbase);

  int cnt = 0;
#pragma unroll
  for (int j = 0; j < 16; ++j) {
    float4 v = s4[j];
    cnt += (v.x >= 0.9f) + (v.y >= 0.9f) + (v.z >= 0.9f) + (v.w >= 0.9f);
  }
  __shared__ int pre[256];
  pre[t] = cnt;
  __syncthreads();
  for (int off = 1; off < 256; off <<= 1) {
    int mine = pre[t];
    int add = (t >= off) ? pre[t - off] : 0;
    __syncthreads();
    pre[t] = mine + add;
    __syncthreads();
  }
  int w = chunkBase[blk] + pre[t] - cnt;

  uint4 z = {0u, 0u, 0u, 0u};
  uint4* lz = (uint4*)(lanes + pixbase);
  lz[0] = z; lz[1] = z; lz[2] = z; lz[3] = z;

  const float* __restrict__ eb = emb + (size_t)b * 8 * HW_;
  const int pixInB = (int)(pixbase - (size_t)b * HW_);
  for (int j = 0; j < 16; ++j) {
    float4 v = s4[j];
    float sv[4] = {v.x, v.y, v.z, v.w};
#pragma unroll
    for (int q = 0; q < 4; ++q) {
      if (sv[q] >= 0.9f && w < cap) {
        const int p = pixInB + j * 4 + q;
        idxC[(size_t)b * cap + w] = p;
        float* dst = embC + ((size_t)b * cap + w) * 8;
#pragma unroll
        for (int dd = 0; dd < 8; ++dd) dst[dd] = eb[(size_t)dd * HW_ + p];
        ++w;
      }
    }
  }
}

// ---------------- sequential clustering: pure-register steady state ----------------
// 8 blocks x 1 wave, one batch each. Centers on lanes 0-31 (32-63 mirror).
// Per tile (32 pixels, 1KB): 1 global_load_lds (64 lanes x 16B) + 1 ds_read_b128
// per lane (lane l keeps bytes [16l,16l+16) of the tile in registers). Per step,
// pixel j's 8 floats are broadcast from lanes 2j / 2j+1 via v_readlane (imm) ->
// SGPRs: zero memory ops in the step, nothing for the compiler to sink.

#define TILE_ 32

__device__ __forceinline__ void stage16(const float* g, float* l) {
  __builtin_amdgcn_global_load_lds(
      (const __attribute__((address_space(1))) void*)g,
      (__attribute__((address_space(3))) void*)l, 16, 0, 0);
}

#define RLF(V, L) __uint_as_float((unsigned)__builtin_amdgcn_readlane(__float_as_int(V), (L)))

#define STEPP(J)                                                                     \
  do {                                                                               \
    const float e0 = RLF(td.x, 2 * (J)), e1 = RLF(td.y, 2 * (J));                    \
    const float e2 = RLF(td.z, 2 * (J)), e3 = RLF(td.w, 2 * (J));                    \
    const float e4 = RLF(td.x, 2 * (J) + 1), e5 = RLF(td.y, 2 * (J) + 1);            \
    const float e6 = RLF(td.z, 2 * (J) + 1), e7 = RLF(td.w, 2 * (J) + 1);            \
    float t0 = C0 - e0, t1 = C1 - e1, t2 = C2 - e2, t3 = C3 - e3;                    \
    float t4 = C4 - e4, t5 = C5 - e5, t6 = C6 - e6, t7 = C7 - e7;                    \
    float a0 = t0 * t0 + t1 * t1;                                                    \
    float a1 = t2 * t2 + t3 * t3;                                                    \
    float a2 = t4 * t4 + t5 * t5;                                                    \
    float a3 = t6 * t6 + t7 * t7;                                                    \
    float dsq = (a0 + a1) + (a2 + a3);                                               \
    unsigned db = __float_as_uint(dsq);                                              \
    unsigned dbm = db > emptyBits ? db : emptyBits; /* empty center -> inf */        \
    unsigned key = (dbm & 0xFFFFFFE0u) | (unsigned)cl; /* v_and_or_b32 */            \
    unsigned mn = key, mr;                                                           \
    mr = (unsigned)__builtin_amdgcn_update_dpp(0, (int)mn, 0xB1, 0xF, 0xF, true);    \
    mn = mn < mr ? mn : mr;                                                          \
    mr = (unsigned)__builtin_amdgcn_update_dpp(0, (int)mn, 0x4E, 0xF, 0xF, true);    \
    mn = mn < mr ? mn : mr;                                                          \
    mr = (unsigned)__builtin_amdgcn_update_dpp(0, (int)mn, 0x141, 0xF, 0xF, true);   \
    mn = mn < mr ? mn : mr;                                                          \
    mr = (unsigned)__builtin_amdgcn_update_dpp(0, (int)mn, 0x140, 0xF, 0xF, true);   \
    mn = mn < mr ? mn : mr;                                                          \
    unsigned q0 = (unsigned)__builtin_amdgcn_readlane((int)mn, 0);                   \
    unsigned q1 = (unsigned)__builtin_amdgcn_readlane((int)mn, 16);                  \
    unsigned mv = q0 < q1 ? q0 : q1; /* uniform -> SALU */                           \
    bool join = mv < 0x41100000u;    /* dsq < 9.0 <=> sqrt(dsq) < 3, exact */        \
    int cid = join ? (int)(mv & 31u) : (nact < 31 ? nact : 31);                      \
    nact += join ? 0 : 1;                                                            \
    bool own = (cl == cid);                                                          \
    float wj = join ? inv : 1.0f;                                                    \
    float w = own ? wj : 0.0f;                                                       \
    C0 = __builtin_fmaf(t0, -w, C0);                                                 \
    C1 = __builtin_fmaf(t1, -w, C1);                                                 \
    C2 = __builtin_fmaf(t2, -w, C2);                                                 \
    C3 = __builtin_fmaf(t3, -w, C3);                                                 \
    C4 = __builtin_fmaf(t4, -w, C4);                                                 \
    C5 = __builtin_fmaf(t5, -w, C5);                                                 \
    C6 = __builtin_fmaf(t6, -w, C6);                                                 \
    C7 = __builtin_fmaf(t7, -w, C7);                                                 \
    cnt += own ? 1.0f : 0.0f;                                                        \
    inv = __builtin_amdgcn_rcpf(cnt + 1.0f); /* off-chain: used next step */         \
    emptyBits = own ? 0u : emptyBits;                                                \
    pk |= (unsigned long long)(unsigned)(cid + 1) << (((J) & 7) * 8);                \
    if (((J) & 7) == 7) {                                                            \
      if (lane == 0) *(unsigned long long*)(cptr + ((J) & ~7)) = pk;                 \
      pk = 0ULL;                                                                     \
    }                                                                                \
  } while (0)

__global__ __launch_bounds__(64, 1) void k_cluster(const float* __restrict__ embC,
                                                   const int* __restrict__ nvalid,
                                                   unsigned char* __restrict__ cidArr,
                                                   int cap) {
  __shared__ float lds[512];  // 2 phases x 256 floats
  const int b = blockIdx.x;
  const int lane = threadIdx.x;
  const int cl = lane & 31;
  const int n = nvalid[b];
  if (n <= 0) return;
  const int nTiles = (n + TILE_ - 1) / TILE_;

  const float* src = embC + (size_t)b * cap * 8 + lane * 4;
  unsigned char* cidB = cidArr + (size_t)b * HW_;

  float C0 = 0.f, C1 = 0.f, C2 = 0.f, C3 = 0.f, C4 = 0.f, C5 = 0.f, C6 = 0.f, C7 = 0.f;
  float cnt = 0.f, inv = 1.0f;
  unsigned emptyBits = 0x7F800000u;
  int nact = 0;
  unsigned long long pk = 0ULL;

  // prologue: stage tile 0, wait, pull my 16B into registers
  stage16(src, lds);
  asm volatile("s_waitcnt vmcnt(0)" ::: "memory");
  __builtin_amdgcn_sched_barrier(0);
  float4 td = ((const float4*)lds)[lane];

  for (int ti = 0; ti < nTiles; ++ti) {
    unsigned char* cptr = cidB + ti * TILE_;
    if (ti + 1 < nTiles)  // stage next tile into the other phase
      stage16(src + (size_t)(ti + 1) * 256, lds + ((ti + 1) & 1) * 128);

    STEPP(0);  STEPP(1);  STEPP(2);  STEPP(3);
    STEPP(4);  STEPP(5);  STEPP(6);  STEPP(7);
    STEPP(8);  STEPP(9);  STEPP(10); STEPP(11);
    STEPP(12); STEPP(13); STEPP(14); STEPP(15);
    STEPP(16); STEPP(17); STEPP(18); STEPP(19);
    STEPP(20); STEPP(21); STEPP(22); STEPP(23);
    STEPP(24); STEPP(25); STEPP(26); STEPP(27);
    STEPP(28); STEPP(29); STEPP(30); STEPP(31);

    if (ti + 1 < nTiles) {
      // outstanding VMEM after stage(ti+1): the stage + 4 lane-0 stores issued
      // after it; in-order retirement => vmcnt(4) <=> stage arrived.
      asm volatile("s_waitcnt vmcnt(4)" ::: "memory");
      __builtin_amdgcn_sched_barrier(0);
      td = ((const float4*)(lds + ((ti + 1) & 1) * 128))[lane];
    }
  }
}

// ---------------- scatter cid bytes to the per-pixel lane map ----------------
__global__ void k_scatter(const unsigned char* __restrict__ cidArr,
                          const int* __restrict__ idxC, const int* __restrict__ nvalid,
                          unsigned char* __restrict__ lanes, int cap) {
  const int b = blockIdx.y;
  const int n = nvalid[b];
  for (int j = blockIdx.x * blockDim.x + threadIdx.x; j < n; j += gridDim.x * blockDim.x) {
    lanes[(size_t)b * HW_ + idxC[(size_t)b * cap + j]] = cidArr[(size_t)b * HW_ + j];
  }
}

// ---------------- per-(b,h) segment sums over 33 lane bins ----------------
__global__ void k_rowsum(const unsigned char* __restrict__ lanes,
                         const float* __restrict__ offp, const float* __restrict__ zp,
                         float* __restrict__ cnt, float* __restrict__ sx,
                         float* __restrict__ sz) {
  const int bh = blockIdx.x;
  const int b = bh >> 9, h = bh & 511;
  __shared__ float sc[33], sxx[33], szz[33];
  const int t = threadIdx.x;
  if (t < 33) { sc[t] = 0.f; sxx[t] = 0.f; szz[t] = 0.f; }
  __syncthreads();
  const size_t base = (size_t)bh * W_;
  for (int x = t; x < W_; x += 256) {
    int ln = lanes[base + x];
    float o = offp[base + x];
    float sig = 1.0f / (1.0f + expf(-o));
    float xa = (float)x + sig;
    float zv = zp[base + x];
    atomicAdd(&sc[ln], 1.0f);
    atomicAdd(&sxx[ln], xa);
    atomicAdd(&szz[ln], zv);
  }
  __syncthreads();
  if (t >= 1 && t < 33) {
    size_t o = ((size_t)b * K_ + (t - 1)) * H_ + h;
    cnt[o] = sc[t]; sx[o] = sxx[t]; sz[o] = szz[t];
  }
}

// ---------------- validity + point assembly ----------------
__global__ void k_final(const float* __restrict__ cnt, const float* __restrict__ sx,
                        const float* __restrict__ sz, float* __restrict__ out) {
  const int bk = blockIdx.x;
  const int b = bk >> 5, k = bk & 31;
  const int h = threadIdx.x;
  const size_t o = (size_t)bk * H_ + h;
  float c = cnt[o];
  float sc_ = c, sn = (c > 0.f) ? 1.f : 0.f;
#pragma unroll
  for (int off = 32; off >= 1; off >>= 1) {
    sc_ += __shfl_down(sc_, off);
    sn += __shfl_down(sn, off);
  }
  __shared__ float rs[8], rn[8], tot[2];
  const int wid = h >> 6, lid = h & 63;
  if (lid == 0) { rs[wid] = sc_; rn[wid] = sn; }
  __syncthreads();
  if (h == 0) {
    float a = 0, bb = 0;
#pragma unroll
    for (int q = 0; q < 8; ++q) { a += rs[q]; bb += rn[q]; }
    tot[0] = a; tot[1] = bb;
  }
  __syncthreads();
  float size = tot[0], nrows = tot[1];
  bool valid = (c > 0.f) && (size >= 50.f) && (nrows >= 2.f);
  float mx = sx[o] / fmaxf(c, 1.f);
  float mz = sz[o] / fmaxf(c, 1.f);
  float xw = (512.0f - ((float)h + 0.5f)) * 0.2f;
  float yw = -(mx - 256.0f) * 0.2f;
  out[((size_t)(b * 3 + 0) * K_ + k) * H_ + h] = valid ? xw : 0.f;
  out[((size_t)(b * 3 + 1) * K_ + k) * H_ + h] = valid ? yw : 0.f;
  out[((size_t)(b * 3 + 2) * K_ + k) * H_ + h] = valid ? mz : 0.f;
  out[(size_t)B_ * 3 * K_ * H_ + (size_t)bk * H_ + h] = valid ? 1.f : 0.f;
}

extern "C" void kernel_launch(void* const* d_in, const int* in_sizes, int n_in,
                              void* d_out, int out_size, void* d_ws, size_t ws_size,
                              hipStream_t stream) {
  const float* seg  = (const float*)d_in[0];
  const float* emb  = (const float*)d_in[1];
  const float* offp = (const float*)d_in[2];
  const float* zp   = (const float*)d_in[3];
  float* out = (float*)d_out;
  char* ws = (char*)d_ws;

  const size_t lanesOff = 0;
  const size_t cntOff   = (size_t)B_ * HW_;
  const size_t sxOff    = cntOff + (size_t)B_ * K_ * H_ * 4;
  const size_t szOff    = sxOff  + (size_t)B_ * K_ * H_ * 4;
  const size_t nvOff    = szOff  + (size_t)B_ * K_ * H_ * 4;
  const size_t ccOff    = nvOff + 256;
  const size_t cbOff    = ccOff + 1024;
  const size_t cidOff   = cbOff + 1024;                      // u8 [B][HW_] = 2 MiB
  const size_t idxOff   = cidOff + (size_t)B_ * HW_;
  size_t avail = (ws_size > idxOff + 4096) ? (ws_size - idxOff - 4096) : 0;  // staging slack
  long long capLL = (long long)(avail / ((size_t)B_ * 36));  // 4B idx + 32B emb per entry
  if (capLL > (long long)HW_) capLL = HW_;
  if (capLL < 1) capLL = 1;
  const int cap = (int)capLL;
  const size_t embOff = idxOff + (size_t)B_ * cap * 4;

  unsigned char* lanes = (unsigned char*)(ws + lanesOff);
  float* cnt = (float*)(ws + cntOff);
  float* sx  = (float*)(ws + sxOff);
  float* sz  = (float*)(ws + szOff);
  int* nvalid = (int*)(ws + nvOff);
  int* chunkCnt  = (int*)(ws + ccOff);
  int* chunkBase = (int*)(ws + cbOff);
  unsigned char* cidArr = (unsigned char*)(ws + cidOff);
  int* idxC   = (int*)(ws + idxOff);
  float* embC = (float*)(ws + embOff);

  k_count<<<B_ * CH_, 256, 0, stream>>>(seg, chunkCnt);
  k_scan<<<1, 128, 0, stream>>>(chunkCnt, chunkBase, nvalid, cap);
  k_fill<<<B_ * CH_, 256, 0, stream>>>(seg, emb, chunkBase, lanes, idxC, embC, cap);
  k_cluster<<<B_, 64, 0, stream>>>(embC, nvalid, cidArr, cap);
  k_scatter<<<dim3(64, B_), 256, 0, stream>>>(cidArr, idxC, nvalid, lanes, cap);
  k_rowsum<<<B_ * H_, 256, 0, stream>>>(lanes, offp, zp, cnt, sx, sz);
  k_final<<<B_ * K_, H_, 0, stream>>>(cnt, sx, sz, out);
}